// Round 9
// baseline (78.434 us; speedup 1.0000x reference)
//
#include <hip/hip_runtime.h>

// Problem constants (fixed by setup_inputs)
#define T_DIM 32
#define B_DIM 64
#define D_DIM 256
#define P_DIM 1024
#define NK    17
#define DT    0.1875f    // 3/16
#define DT_REV 0.029841551329651566f   // DT / (2*pi) -- v_sin/v_cos take revolutions

typedef __bf16 bf16x8 __attribute__((ext_vector_type(8)));
typedef float  f32x16 __attribute__((ext_vector_type(16)));

// Native bf16 pack: lowers to v_cvt_pk_bf16_f32 (RNE).
static __device__ __forceinline__ unsigned pkbf(float lo, float hi) {
  unsigned short a = __builtin_bit_cast(unsigned short, (__bf16)lo);
  unsigned short b = __builtin_bit_cast(unsigned short, (__bf16)hi);
  return (unsigned)a | ((unsigned)b << 16);
}

// Opaque zero derived from x: forces the wave to wait for x (s_waitcnt) and
// gives the compiler an unfoldable data dependency.
static __device__ __forceinline__ int dep_zero(float x) {
  int d;
  asm volatile("v_and_b32 %0, 0, %1" : "=v"(d) : "v"(x));
  return d;
}

// Module-scope scratch (load-time zero-init; NOT poisoned by the harness).
// ALL accesses RELAXED device-scope atomics (R4/R5: ordered agent-scope ops
// poison L2 on non-coherent XCDs). Flat structure (R6/R7 proven).
// Counter never reset; last-arrival test (old & 1023)==1023 is wrap-safe.
__device__ float g_sum[64 * 32];
__device__ int   g_counter = 0;

// ---------------------------------------------------------------------------
// No-staging redesign. Single dispatch, no memset.
// grid (32 ptile, 32 t) x 128 thr (2 waves). 1024 blocks, 8 waves/CU.
// Wave wv owns output tile b = wv*32..+31 (rows), p = p0..p0+31 (cols).
//  - A-frag (proj row, k-contiguous): 2x float4 per k-step, global->reg.
//  - B-frag (A^T): for fixed k, lanes 0..31 read A[k][p0..p0+31] = 128 B
//    contiguous -> 8 coalesced dword loads per k-step give each lane its
//    fragment directly. NO LDS staging, NO transpose, NO stage barriers.
//  - column sq-norm: same loaded values, own 128 k's + shfl_xor(32) -> full.
//  - 16 back-to-back 32x32x16 bf16 MFMAs (same k-order as R8 -> x identical).
//  - HW trig + Chebyshev recurrence (verbatim R8).
//  - cross-wave b-half combine: wave1 writes cs/ss (32 p x 32 f32, +1 pad)
//    to a 4.2 KB LDS exchange; ONE barrier; wave0 combines in-register,
//    evaluates all 16 harmonics' error terms, wave-reduces.
//  - tail: R7/R8 flat relaxed atomic protocol (mask 1023).
// LDS: 4224 B/block. Barriers: 1.
// ---------------------------------------------------------------------------
__global__ __launch_bounds__(128) void sig_fused_kernel(const float* __restrict__ proj,
                                                        const float* __restrict__ A,
                                                        float* __restrict__ out) {
  __shared__ float exch[32 * 33];                // 4224 B

  const int tid  = threadIdx.x;
  const int lane = tid & 63;
  const int wv   = tid >> 6;                     // 0/1 = b-half
  const int p0   = blockIdx.x * 32;
  const int t    = blockIdx.y;

  const int l31 = lane & 31;
  const int hi  = lane >> 5;                     // k-sub half

  // A-operand row of this lane: proj[t][wv*32 + l31][ks*16 + hi*8 .. +8]
  const float* Pr = proj + ((size_t)t * B_DIM + wv * 32 + l31) * D_DIM + hi * 8;
  // B-operand column of this lane: A[k][p0 + l31], k = ks*16 + hi*8 + j
  const float* Ac = A + p0 + l31 + (size_t)hi * 8 * P_DIM;

  f32x16 acc = {0.f, 0.f, 0.f, 0.f, 0.f, 0.f, 0.f, 0.f,
                0.f, 0.f, 0.f, 0.f, 0.f, 0.f, 0.f, 0.f};
  float nrm = 0.f;

#pragma unroll 4
  for (int ks = 0; ks < 16; ++ks) {
    float4 u0 = *(const float4*)(Pr + ks * 16);
    float4 u1 = *(const float4*)(Pr + ks * 16 + 4);
    const float* ak = Ac + (size_t)ks * 16 * P_DIM;
    float a0 = ak[0 * P_DIM], a1 = ak[1 * P_DIM];
    float a2 = ak[2 * P_DIM], a3 = ak[3 * P_DIM];
    float a4 = ak[4 * P_DIM], a5 = ak[5 * P_DIM];
    float a6 = ak[6 * P_DIM], a7 = ak[7 * P_DIM];
    nrm = fmaf(a0, a0, nrm); nrm = fmaf(a1, a1, nrm);
    nrm = fmaf(a2, a2, nrm); nrm = fmaf(a3, a3, nrm);
    nrm = fmaf(a4, a4, nrm); nrm = fmaf(a5, a5, nrm);
    nrm = fmaf(a6, a6, nrm); nrm = fmaf(a7, a7, nrm);
    union { bf16x8 v; unsigned u[4]; } wa, wb;
    wa.u[0] = pkbf(u0.x, u0.y);
    wa.u[1] = pkbf(u0.z, u0.w);
    wa.u[2] = pkbf(u1.x, u1.y);
    wa.u[3] = pkbf(u1.z, u1.w);
    wb.u[0] = pkbf(a0, a1);
    wb.u[1] = pkbf(a2, a3);
    wb.u[2] = pkbf(a4, a5);
    wb.u[3] = pkbf(a6, a7);
    acc = __builtin_amdgcn_mfma_f32_32x32x16_bf16(wa.v, wb.v, acc, 0, 0, 0);
  }
  // acc reg r = x_unnorm[b = wv*32+(r&3)+8*(r>>2)+4*hi][p = p0+l31]

  // ---- full column norm: own 128 k's + partner half ----
  nrm += __shfl_xor(nrm, 32, 64);
  // scale to REVOLUTIONS: theta = x*DT, hw trig wants theta/2pi
  const float invdt = rsqrtf(fmaxf(nrm, 1e-24f)) * DT_REV; // 1/clamp_min(norm)

  // ---- Chebyshev trig via HW v_sin/v_cos: sums over this lane's 16 b's ----
  float cs[NK - 1], ss[NK - 1];
#pragma unroll
  for (int k = 0; k < NK - 1; ++k) { cs[k] = 0.f; ss[k] = 0.f; }
#pragma unroll
  for (int r = 0; r < 16; ++r) {
    float th = acc[r] * invdt;                   // revolutions, |th| << 1
    float c1 = __builtin_amdgcn_cosf(th);        // v_cos_f32: cos(2*pi*th)
    float s1 = __builtin_amdgcn_sinf(th);        // v_sin_f32: sin(2*pi*th)
    float twoc = 2.f * c1;
    float ckm1 = 1.f, skm1 = 0.f;
    float ck = c1, sk = s1;
    cs[0] += c1;
    ss[0] += s1;
#pragma unroll
    for (int k = 2; k < NK; ++k) {
      float cn = fmaf(twoc, ck, -ckm1);
      float sn = fmaf(twoc, sk, -skm1);
      cs[k - 1] += cn;
      ss[k - 1] += sn;
      ckm1 = ck; skm1 = sk; ck = cn; sk = sn;
    }
  }

  // ---- combine the two hi-halves (lane L and L^32 share the same p col) ----
#pragma unroll
  for (int k = 0; k < NK - 1; ++k) {
    cs[k] += __shfl_xor(cs[k], 32, 64);
    ss[k] += __shfl_xor(ss[k], 32, 64);
  }
  // now each lane holds this wave's 32-b sums for p = p0 + l31

  // ---- wave1 exports to LDS (33-float pad: bank (l31+k)%32, no conflict) --
  if (wv == 1 && lane < 32) {
    float* row = &exch[l31 * 33];
#pragma unroll
    for (int k = 0; k < NK - 1; ++k) {
      row[k]      = cs[k];
      row[16 + k] = ss[k];
    }
  }
  __syncthreads();                               // (1) the only barrier

  // ---- wave0: combine + all-16-harmonics error, wave-reduce, tail ----
  if (wv == 0) {
    const float* row = &exch[l31 * 33];
    float part = 0.f;
#pragma unroll
    for (int k = 0; k < NK - 1; ++k) {
      float C = cs[k] + row[k];
      float S = ss[k] + row[16 + k];
      float cm  = C * (1.f / 64.f);
      float sm_ = S * (1.f / 64.f);
      float tk  = (float)(k + 1) * DT;
      float phi = __expf(-0.5f * tk * tk);
      float wk  = ((k == NK - 2) ? DT : 2.f * DT) * phi;  // k=16 endpoint
      float dc  = cm - phi;
      part = fmaf(wk, fmaf(dc, dc, sm_ * sm_), part);
    }
    // hi-halves duplicate -> wave sum double-counts 2x: (1/512)/2
    part *= (1.f / 1024.f);
#pragma unroll
    for (int off = 32; off > 0; off >>= 1)
      part += __shfl_down(part, off, 64);

    // ---- flat relaxed tail (R7/R8 proven; mask now 1023) ----
    const int bid = t * 32 + blockIdx.x;         // 0..1023
    int isl = 0;
    if (lane == 0) {
      float oldv = atomicAdd(&g_sum[(bid & 63) * 32], part);
      // dep_zero: sum-RMW provably performed before the counter bump issues
      int oc = atomicAdd(&g_counter, 1 + dep_zero(oldv));
      isl = ((oc & 1023) == 1023);               // wrap-safe across replays
    }
    isl = __shfl(isl, 0, 64);
    if (isl) {
      // All 1024 sum-RMWs performed (counter protocol). 64 parallel
      // exchanges gather + re-arm each line in one round trip.
      float s = atomicExch(&g_sum[lane * 32], 0.0f);
#pragma unroll
      for (int off = 32; off > 0; off >>= 1)
        s += __shfl_down(s, off, 64);
      if (lane == 0) out[0] = s;                 // overwrite poison
    }
  }
}

// ---------------------------------------------------------------------------
extern "C" void kernel_launch(void* const* d_in, const int* in_sizes, int n_in,
                              void* d_out, int out_size, void* d_ws, size_t ws_size,
                              hipStream_t stream) {
  const float* proj = (const float*)d_in[0];     // (32,64,256) fp32
  const float* A    = (const float*)d_in[1];     // (256,1024) fp32
  float* out        = (float*)d_out;             // 1 fp32 scalar

  // ONE dispatch: no memset -- the finishing block plain-stores the scalar.
  sig_fused_kernel<<<dim3(32, 32), dim3(128), 0, stream>>>(proj, A, out);
}

// Round 10
// 75.304 us; speedup vs baseline: 1.0416x; 1.0416x over previous
//
#include <hip/hip_runtime.h>

// Problem constants (fixed by setup_inputs)
#define T_DIM 32
#define B_DIM 64
#define D_DIM 256
#define P_DIM 1024
#define NK    17
#define DT    0.1875f    // 3/16
#define DT_REV 0.029841551329651566f   // DT / (2*pi) -- v_sin/v_cos take revolutions

#define LROWA 264        // padded A^T row in bf16 (256+8)

typedef __bf16 bf16x8 __attribute__((ext_vector_type(8)));
typedef float  f32x16 __attribute__((ext_vector_type(16)));

// Native bf16 pack: lowers to v_cvt_pk_bf16_f32 (RNE).
static __device__ __forceinline__ unsigned pkbf(float lo, float hi) {
  unsigned short a = __builtin_bit_cast(unsigned short, (__bf16)lo);
  unsigned short b = __builtin_bit_cast(unsigned short, (__bf16)hi);
  return (unsigned)a | ((unsigned)b << 16);
}

// Opaque zero derived from x: forces the wave to wait for x (s_waitcnt) and
// gives the compiler an unfoldable data dependency.
static __device__ __forceinline__ int dep_zero(float x) {
  int d;
  asm volatile("v_and_b32 %0, 0, %1" : "=v"(d) : "v"(x));
  return d;
}

// Module-scope scratch (load-time zero-init; NOT poisoned by the harness).
// ALL accesses RELAXED device-scope atomics (R4/R5: ordered agent-scope ops
// poison L2 on non-coherent XCDs). Flat structure (R6-R9 proven).
// Counter never reset; last-arrival test (old & 1023)==1023 is wrap-safe.
__device__ float g_sum[64 * 32];
__device__ int   g_counter = 0;

// ---------------------------------------------------------------------------
// R8 structure at HALF block granularity (R9 post-mortem: keep LDS staging;
// the lever is block concurrency, not barrier count).
// grid (32 ptile, 32 t) x 128 thr (2 waves) = 1024 blocks -> 4 blocks/CU
// (was 2), phases desynchronize across blocks; per-block stage = 32 KB.
//  - proj MFMA fragments global->register, fp32->bf16 native casts (R8)
//  - A staged once (full K=256, 32 p-cols) into LDS transposed [p][k] bf16;
//    fp32 column sq-norm partials during staging (norm after GEMM)
//  - 16 back-to-back 32x32x16 bf16 MFMAs, one 32x32 tile per wave
//    (wv = b-half), same k-order as R8 -> identical x values
//  - HW trig + Chebyshev recurrence (verbatim R8)
//  - epilogue: wave1 exports cs/ss to a padded exchange region ALIASING the
//    dead A-tile; one barrier; wave0 combines in-register, evaluates all 16
//    harmonics, wave-reduces (verbatim R8/R9 math, scale 1/1024)
//  - tail: R9's flat relaxed atomic protocol, verbatim (mask 1023)
// LDS (floats): sa 0..4223 (16896 B) | normred[16][32] @4224 | invn[32]
//   @4736 | exch [32][33] aliases sa (written post-barrier (2), sa dead).
//   19072 B/block. Barriers: 3 (128-thr each).
// ---------------------------------------------------------------------------
__global__ __launch_bounds__(128) void sig_fused_kernel(const float* __restrict__ proj,
                                                        const float* __restrict__ A,
                                                        float* __restrict__ out) {
  __shared__ float smf[4768];
  unsigned short* sa = (unsigned short*)smf;     // A^T tile [32 p][264 k]
  float* normred = smf + 4224;                   // [16 kg][32 p]
  float* invn    = smf + 4736;                   // [32]
  float* exch    = smf;                          // aliases sa (safe post-(2))

  const int tid  = threadIdx.x;
  const int lane = tid & 63;
  const int wv   = tid >> 6;                     // 0/1 = b-half
  const int p0   = blockIdx.x * 32;
  const int t    = blockIdx.y;

  const int l31 = lane & 31;
  const int hi  = lane >> 5;                     // k-sub half

  // ---- proj fragments: direct global->reg, convert to bf16 ----
  const float* Pr = proj + ((size_t)t * B_DIM + wv * 32 + l31) * D_DIM + hi * 8;
  bf16x8 af[16];
#pragma unroll
  for (int ks = 0; ks < 16; ++ks) {
    float4 u0 = *(const float4*)(Pr + ks * 16);
    float4 u1 = *(const float4*)(Pr + ks * 16 + 4);
    union { bf16x8 v; unsigned u[4]; } w;
    w.u[0] = pkbf(u0.x, u0.y);
    w.u[1] = pkbf(u0.z, u0.w);
    w.u[2] = pkbf(u1.x, u1.y);
    w.u[3] = pkbf(u1.z, u1.w);
    af[ks] = w.v;
  }

  // ---- A-stage: full K, 32 p-cols, transpose + convert + norm partials ----
  {
    const int pg = tid & 7;                      // p-group (4 p's), 8 groups
    const int kg = tid >> 3;                     // 0..15, 16 k's each
    const float4* Ag = (const float4*)(A + p0); // row stride P_DIM/4 float4
    float4 va[16];
#pragma unroll
    for (int i = 0; i < 16; ++i)
      va[i] = Ag[(size_t)(kg * 16 + i) * (P_DIM / 4) + pg];
    float nrm[4] = {0.f, 0.f, 0.f, 0.f};
#pragma unroll
    for (int j = 0; j < 4; ++j) {
#pragma unroll
      for (int h = 0; h < 2; ++h) {
        float e0 = ((const float*)&va[h * 8 + 0])[j];
        float e1 = ((const float*)&va[h * 8 + 1])[j];
        float e2 = ((const float*)&va[h * 8 + 2])[j];
        float e3 = ((const float*)&va[h * 8 + 3])[j];
        float e4 = ((const float*)&va[h * 8 + 4])[j];
        float e5 = ((const float*)&va[h * 8 + 5])[j];
        float e6 = ((const float*)&va[h * 8 + 6])[j];
        float e7 = ((const float*)&va[h * 8 + 7])[j];
        nrm[j] = fmaf(e0, e0, nrm[j]); nrm[j] = fmaf(e1, e1, nrm[j]);
        nrm[j] = fmaf(e2, e2, nrm[j]); nrm[j] = fmaf(e3, e3, nrm[j]);
        nrm[j] = fmaf(e4, e4, nrm[j]); nrm[j] = fmaf(e5, e5, nrm[j]);
        nrm[j] = fmaf(e6, e6, nrm[j]); nrm[j] = fmaf(e7, e7, nrm[j]);
        uint4 w;
        w.x = pkbf(e0, e1);
        w.y = pkbf(e2, e3);
        w.z = pkbf(e4, e5);
        w.w = pkbf(e6, e7);
        *(uint4*)&sa[(pg * 4 + j) * LROWA + kg * 16 + h * 8] = w;
      }
      normred[kg * 32 + pg * 4 + j] = nrm[j];
    }
  }
  __syncthreads();                               // (1) A tile + normred ready

  // ---- finish column norms -> invn[p] (overlaps partner wave's MFMA) ----
  if (tid < 32) {
    float s = 0.f;
#pragma unroll
    for (int q = 0; q < 16; ++q) s += normred[q * 32 + tid];
    invn[tid] = rsqrtf(fmaxf(s, 1e-24f));        // 1/clamp_min(norm, 1e-12)
  }

  // ---- MFMA: 16 k-steps over full K ----
  f32x16 acc = {0.f, 0.f, 0.f, 0.f, 0.f, 0.f, 0.f, 0.f,
                0.f, 0.f, 0.f, 0.f, 0.f, 0.f, 0.f, 0.f};
  const unsigned short* brow = &sa[l31 * LROWA + hi * 8];
#pragma unroll
  for (int ks = 0; ks < 16; ++ks) {
    bf16x8 bfr = *(const bf16x8*)(brow + ks * 16);
    acc = __builtin_amdgcn_mfma_f32_32x32x16_bf16(af[ks], bfr, acc, 0, 0, 0);
  }
  // acc reg r = x_unnorm[b = wv*32+(r&3)+8*(r>>2)+4*hi][p = p0+l31]
  __syncthreads();                               // (2) invn ready; sa dead

  // scale to REVOLUTIONS: theta = x*DT, hw trig wants theta/2pi
  const float invdt = invn[l31] * DT_REV;

  // ---- Chebyshev trig via HW v_sin/v_cos: sums over this lane's 16 b's ----
  float cs[NK - 1], ss[NK - 1];
#pragma unroll
  for (int k = 0; k < NK - 1; ++k) { cs[k] = 0.f; ss[k] = 0.f; }
#pragma unroll
  for (int r = 0; r < 16; ++r) {
    float th = acc[r] * invdt;                   // revolutions, |th| << 1
    float c1 = __builtin_amdgcn_cosf(th);        // v_cos_f32: cos(2*pi*th)
    float s1 = __builtin_amdgcn_sinf(th);        // v_sin_f32: sin(2*pi*th)
    float twoc = 2.f * c1;
    float ckm1 = 1.f, skm1 = 0.f;
    float ck = c1, sk = s1;
    cs[0] += c1;
    ss[0] += s1;
#pragma unroll
    for (int k = 2; k < NK; ++k) {
      float cn = fmaf(twoc, ck, -ckm1);
      float sn = fmaf(twoc, sk, -skm1);
      cs[k - 1] += cn;
      ss[k - 1] += sn;
      ckm1 = ck; skm1 = sk; ck = cn; sk = sn;
    }
  }

  // ---- combine the two hi-halves (lane L and L^32 share the same p col) ----
#pragma unroll
  for (int k = 0; k < NK - 1; ++k) {
    cs[k] += __shfl_xor(cs[k], 32, 64);
    ss[k] += __shfl_xor(ss[k], 32, 64);
  }
  // each lane now holds this wave's 32-b sums for p = p0 + l31

  // ---- wave1 exports to exch (aliases dead sa; 33-f pad, conflict-free) --
  if (wv == 1 && lane < 32) {
    float* row = &exch[l31 * 33];
#pragma unroll
    for (int k = 0; k < NK - 1; ++k) {
      row[k]      = cs[k];
      row[16 + k] = ss[k];
    }
  }
  __syncthreads();                               // (3) exch ready

  // ---- wave0: combine + all-16-harmonics error, wave-reduce, tail ----
  if (wv == 0) {
    const float* row = &exch[l31 * 33];
    float part = 0.f;
#pragma unroll
    for (int k = 0; k < NK - 1; ++k) {
      float C = cs[k] + row[k];
      float S = ss[k] + row[16 + k];
      float cm  = C * (1.f / 64.f);
      float sm_ = S * (1.f / 64.f);
      float tk  = (float)(k + 1) * DT;
      float phi = __expf(-0.5f * tk * tk);
      float wk  = ((k == NK - 2) ? DT : 2.f * DT) * phi;  // k=16 endpoint
      float dc  = cm - phi;
      part = fmaf(wk, fmaf(dc, dc, sm_ * sm_), part);
    }
    // hi-halves duplicate -> wave sum double-counts 2x: (1/512)/2
    part *= (1.f / 1024.f);
#pragma unroll
    for (int off = 32; off > 0; off >>= 1)
      part += __shfl_down(part, off, 64);

    // ---- flat relaxed tail (R9 proven): spread lines + one counter ----
    const int bid = t * 32 + blockIdx.x;         // 0..1023
    int isl = 0;
    if (lane == 0) {
      float oldv = atomicAdd(&g_sum[(bid & 63) * 32], part);
      // dep_zero: sum-RMW provably performed before the counter bump issues
      int oc = atomicAdd(&g_counter, 1 + dep_zero(oldv));
      isl = ((oc & 1023) == 1023);               // wrap-safe across replays
    }
    isl = __shfl(isl, 0, 64);
    if (isl) {
      // All 1024 sum-RMWs performed (counter protocol). 64 parallel
      // exchanges gather + re-arm each line in one round trip.
      float s = atomicExch(&g_sum[lane * 32], 0.0f);
#pragma unroll
      for (int off = 32; off > 0; off >>= 1)
        s += __shfl_down(s, off, 64);
      if (lane == 0) out[0] = s;                 // overwrite poison
    }
  }
}

// ---------------------------------------------------------------------------
extern "C" void kernel_launch(void* const* d_in, const int* in_sizes, int n_in,
                              void* d_out, int out_size, void* d_ws, size_t ws_size,
                              hipStream_t stream) {
  const float* proj = (const float*)d_in[0];     // (32,64,256) fp32
  const float* A    = (const float*)d_in[1];     // (256,1024) fp32
  float* out        = (float*)d_out;             // 1 fp32 scalar

  // ONE dispatch: no memset -- the finishing block plain-stores the scalar.
  sig_fused_kernel<<<dim3(32, 32), dim3(128), 0, stream>>>(proj, A, out);
}